// Round 1
// baseline (10726.324 us; speedup 1.0000x reference)
//
#include <hip/hip_runtime.h>
#include <hip/hip_bf16.h>
#include <math.h>

#define N_NODES 50000
#define N_EDGES 800000
#define DIN     384
#define HID     256
#define HEADS   4
#define CDIM    64
#define EDIM    32
#define ETOT    (N_EDGES + N_NODES)   // 850000
#define SLOPE   0.2f
#define LN_EPS  1e-5f

// ---- float <-> order-preserving uint key (for atomicMax on floats) ----
__device__ __forceinline__ unsigned fkey(float f) {
    unsigned u = __float_as_uint(f);
    return (u & 0x80000000u) ? ~u : (u | 0x80000000u);
}
__device__ __forceinline__ float funkey(unsigned k) {
    unsigned u = (k & 0x80000000u) ? (k & 0x7fffffffu) : ~k;
    return __uint_as_float(u);
}

// ---------------- deg + loop_ea accumulation ----------------
// one thread per (edge, k) pair; k==0 also bumps degree
__global__ void deg_loopea_kernel(const int* __restrict__ dst,
                                  const float* __restrict__ edge_attr,
                                  float* __restrict__ loop_ea,
                                  float* __restrict__ deg) {
    size_t i = (size_t)blockIdx.x * 256 + threadIdx.x;
    if (i >= (size_t)N_EDGES * EDIM) return;
    int e = (int)(i >> 5);
    int k = (int)(i & 31);
    int d = dst[e];
    atomicAdd(loop_ea + (size_t)d * EDIM + k, edge_attr[i]);
    if (k == 0) atomicAdd(deg + d, 1.0f);
}

__global__ void loopea_div_kernel(float* __restrict__ loop_ea,
                                  const float* __restrict__ deg) {
    size_t i = (size_t)blockIdx.x * 256 + threadIdx.x;
    if (i >= (size_t)N_NODES * EDIM) return;
    int n = (int)(i >> 5);
    loop_ea[i] /= fmaxf(deg[n], 1.0f);
}

// ---------------- generic fp32 tiled GEMM: C = act(A@B + bias) ----------------
// A [M,K] row-major, B [K,N] row-major, N multiple of 64, K multiple of 16.
__launch_bounds__(256)
__global__ void gemm_kernel(const float* __restrict__ A, const float* __restrict__ B,
                            const float* __restrict__ bias, float* __restrict__ C,
                            int M, int K, int N, int act) {
    __shared__ float As[16][68];
    __shared__ float Bs[16][68];
    const int tid  = threadIdx.x;
    const int row0 = blockIdx.y * 64;
    const int col0 = blockIdx.x * 64;
    const int tx = tid & 15, ty = tid >> 4;
    const int la_r = tid >> 2;          // 0..63
    const int la_c = (tid & 3) * 4;     // 0,4,8,12
    const int lb_r = tid >> 4;          // 0..15
    const int lb_c = (tid & 15) * 4;    // 0..60
    float acc[4][4] = {};

    for (int k0 = 0; k0 < K; k0 += 16) {
        int ar = row0 + la_r;
        float4 av = make_float4(0.f, 0.f, 0.f, 0.f);
        if (ar < M) av = *reinterpret_cast<const float4*>(A + (size_t)ar * K + k0 + la_c);
        As[la_c + 0][la_r] = av.x;
        As[la_c + 1][la_r] = av.y;
        As[la_c + 2][la_r] = av.z;
        As[la_c + 3][la_r] = av.w;
        float4 bv = *reinterpret_cast<const float4*>(B + (size_t)(k0 + lb_r) * N + col0 + lb_c);
        *reinterpret_cast<float4*>(&Bs[lb_r][lb_c]) = bv;
        __syncthreads();
#pragma unroll
        for (int kk = 0; kk < 16; ++kk) {
            float a0 = As[kk][ty * 4 + 0];
            float a1 = As[kk][ty * 4 + 1];
            float a2 = As[kk][ty * 4 + 2];
            float a3 = As[kk][ty * 4 + 3];
            float4 b = *reinterpret_cast<const float4*>(&Bs[kk][tx * 4]);
            acc[0][0] += a0 * b.x; acc[0][1] += a0 * b.y; acc[0][2] += a0 * b.z; acc[0][3] += a0 * b.w;
            acc[1][0] += a1 * b.x; acc[1][1] += a1 * b.y; acc[1][2] += a1 * b.z; acc[1][3] += a1 * b.w;
            acc[2][0] += a2 * b.x; acc[2][1] += a2 * b.y; acc[2][2] += a2 * b.z; acc[2][3] += a2 * b.w;
            acc[3][0] += a3 * b.x; acc[3][1] += a3 * b.y; acc[3][2] += a3 * b.z; acc[3][3] += a3 * b.w;
        }
        __syncthreads();
    }
#pragma unroll
    for (int i = 0; i < 4; ++i) {
        int r = row0 + ty * 4 + i;
        if (r >= M) break;
#pragma unroll
        for (int j = 0; j < 4; ++j) {
            int c = col0 + tx * 4 + j;
            float v = acc[i][j];
            if (bias) v += bias[c];
            if (act) v = fmaxf(v, 0.f);
            C[(size_t)r * N + c] = v;
        }
    }
}

// ---------------- edge logits + segment max ----------------
__launch_bounds__(256)
__global__ void edge_logits_kernel(const float* __restrict__ xl, const float* __restrict__ xr,
                                   const float* __restrict__ edge_attr, const float* __restrict__ loop_ea,
                                   const int* __restrict__ src, const int* __restrict__ dst,
                                   const float* __restrict__ we, const float* __restrict__ att,
                                   float* __restrict__ logits, unsigned int* __restrict__ lmaxk) {
    __shared__ float we_s[EDIM][HID];    // 32 KB
    __shared__ float att_s[HID];
    for (int i = threadIdx.x; i < EDIM * HID; i += 256) we_s[i >> 8][i & 255] = we[i];
    if (threadIdx.x < HID) att_s[threadIdx.x] = att[threadIdx.x];
    __syncthreads();
    const int lane = threadIdx.x & 63;
    const int wave = threadIdx.x >> 6;
    const int c0   = lane * 4;
    const int head = lane >> 4;
    for (int e = blockIdx.x * 4 + wave; e < ETOT; e += gridDim.x * 4) {
        int s, d;
        float eav = 0.f;
        if (e < N_EDGES) {
            s = src[e]; d = dst[e];
            if (lane < EDIM) eav = edge_attr[(size_t)e * EDIM + lane];
        } else {
            s = e - N_EDGES; d = s;
            if (lane < EDIM) eav = loop_ea[(size_t)s * EDIM + lane];
        }
        float4 ep = make_float4(0.f, 0.f, 0.f, 0.f);
#pragma unroll
        for (int k = 0; k < EDIM; ++k) {
            float a = __shfl(eav, k, 64);
            float4 w4 = *reinterpret_cast<const float4*>(&we_s[k][c0]);
            ep.x += a * w4.x; ep.y += a * w4.y; ep.z += a * w4.z; ep.w += a * w4.w;
        }
        float4 xlv = *reinterpret_cast<const float4*>(xl + (size_t)s * HID + c0);
        float4 xrv = *reinterpret_cast<const float4*>(xr + (size_t)d * HID + c0);
        float m0 = xlv.x + xrv.x + ep.x; m0 = m0 > 0.f ? m0 : SLOPE * m0;
        float m1 = xlv.y + xrv.y + ep.y; m1 = m1 > 0.f ? m1 : SLOPE * m1;
        float m2 = xlv.z + xrv.z + ep.z; m2 = m2 > 0.f ? m2 : SLOPE * m2;
        float m3 = xlv.w + xrv.w + ep.w; m3 = m3 > 0.f ? m3 : SLOPE * m3;
        float part = m0 * att_s[c0] + m1 * att_s[c0 + 1] + m2 * att_s[c0 + 2] + m3 * att_s[c0 + 3];
        part += __shfl_xor(part, 8, 64);
        part += __shfl_xor(part, 4, 64);
        part += __shfl_xor(part, 2, 64);
        part += __shfl_xor(part, 1, 64);
        if ((lane & 15) == 0) {
            logits[(size_t)e * HEADS + head] = part;
            atomicMax(lmaxk + (size_t)d * HEADS + head, fkey(part));
        }
    }
}

// ---------------- exp + denom ----------------
__global__ void exp_denom_kernel(const int* __restrict__ dst, const unsigned int* __restrict__ lmaxk,
                                 float* __restrict__ logits, float* __restrict__ denom) {
    size_t i = (size_t)blockIdx.x * 256 + threadIdx.x;
    if (i >= (size_t)ETOT * HEADS) return;
    int e  = (int)(i >> 2);
    int hh = (int)(i & 3);
    int d  = (e < N_EDGES) ? dst[e] : (e - N_EDGES);
    float lm = funkey(lmaxk[(size_t)d * HEADS + hh]);
    float ex = expf(logits[i] - lm);
    logits[i] = ex;
    atomicAdd(denom + (size_t)d * HEADS + hh, ex);
}

// ---------------- alpha-weighted scatter ----------------
__launch_bounds__(256)
__global__ void scatter_kernel(const float* __restrict__ xl, const float* __restrict__ ex,
                               const float* __restrict__ denom,
                               const int* __restrict__ src, const int* __restrict__ dst,
                               float* __restrict__ acc) {
    const int lane = threadIdx.x & 63;
    const int wave = threadIdx.x >> 6;
    const int c0   = lane * 4;
    const int head = lane >> 4;
    for (int e = blockIdx.x * 4 + wave; e < ETOT; e += gridDim.x * 4) {
        int s, d;
        if (e < N_EDGES) { s = src[e]; d = dst[e]; }
        else             { s = e - N_EDGES; d = s; }
        float alpha = ex[(size_t)e * HEADS + head] /
                      (denom[(size_t)d * HEADS + head] + 1e-16f);
        float4 xlv = *reinterpret_cast<const float4*>(xl + (size_t)s * HID + c0);
        float* out = acc + (size_t)d * HID + c0;
        atomicAdd(out + 0, alpha * xlv.x);
        atomicAdd(out + 1, alpha * xlv.y);
        atomicAdd(out + 2, alpha * xlv.z);
        atomicAdd(out + 3, alpha * xlv.w);
    }
}

// ---------------- h += elu(acc + b_conv); accumulate global sum/sumsq ----------------
__launch_bounds__(256)
__global__ void update_reduce_kernel(float* __restrict__ h, const float* __restrict__ acc,
                                     const float* __restrict__ bconv, float* __restrict__ red) {
    __shared__ float s_sum[4], s_sq[4];
    size_t i = (size_t)blockIdx.x * 256 + threadIdx.x;   // grid covers N*HID exactly
    int col = (int)(i & 255);
    float v = acc[i] + bconv[col];
    v = v > 0.f ? v : expm1f(v);
    float hn = h[i] + v;
    h[i] = hn;
    float sm = hn, sq = hn * hn;
#pragma unroll
    for (int o = 32; o; o >>= 1) {
        sm += __shfl_down(sm, o, 64);
        sq += __shfl_down(sq, o, 64);
    }
    int lane = threadIdx.x & 63, wv = threadIdx.x >> 6;
    if (lane == 0) { s_sum[wv] = sm; s_sq[wv] = sq; }
    __syncthreads();
    if (threadIdx.x == 0) {
        sm = s_sum[0] + s_sum[1] + s_sum[2] + s_sum[3];
        sq = s_sq[0] + s_sq[1] + s_sq[2] + s_sq[3];
        atomicAdd(red + 0, sm);
        atomicAdd(red + 1, sq);
    }
}

// ---------------- graph layernorm apply ----------------
__global__ void ln_kernel(float* __restrict__ h, const float* __restrict__ red,
                          const float* __restrict__ lnw, const float* __restrict__ lnb) {
    size_t i = (size_t)blockIdx.x * 256 + threadIdx.x;
    if (i >= (size_t)N_NODES * HID) return;
    int col = (int)(i & 255);
    const float inv_cnt = 1.f / (float)((size_t)N_NODES * HID);
    float mu = red[0] * inv_cnt;
    float ms = red[1] * inv_cnt - mu * mu;
    float stdv = sqrtf(fmaxf(ms, 0.f));
    float sc = 1.f / (stdv + LN_EPS);
    h[i] = (h[i] - mu) * sc * lnw[col] + lnb[col];
}

extern "C" void kernel_launch(void* const* d_in, const int* in_sizes, int n_in,
                              void* d_out, int out_size, void* d_ws, size_t ws_size,
                              hipStream_t stream) {
    (void)in_sizes; (void)n_in; (void)out_size; (void)ws_size;
    const float* x      = (const float*)d_in[0];
    const int*   ei     = (const int*)d_in[1];
    const float* eattr  = (const float*)d_in[2];
    const float* w_in   = (const float*)d_in[3];
    const float* b_in   = (const float*)d_in[4];
    const float* wl     = (const float*)d_in[5];
    const float* wr     = (const float*)d_in[6];
    const float* we     = (const float*)d_in[7];
    const float* att    = (const float*)d_in[8];
    const float* b_conv = (const float*)d_in[9];
    const float* ln_w   = (const float*)d_in[10];
    const float* ln_b   = (const float*)d_in[11];
    const float* w_out  = (const float*)d_in[12];
    const float* b_out  = (const float*)d_in[13];
    const int* srcp = ei;
    const int* dstp = ei + N_EDGES;

    float* ws = (float*)d_ws;
    float*    h     = ws;                          // 12,800,000
    float*    xl    = ws + 12800000;               // 12,800,000
    float*    xr    = ws + 25600000;               // 12,800,000
    float*    accb  = ws + 38400000;               // 12,800,000
    float*    lpea  = ws + 51200000;               //  1,600,000
    float*    deg   = ws + 52800000;               //     64,000 (padded)
    float*    lgt   = ws + 52864000;               //  3,400,000
    unsigned* lmaxk = (unsigned*)(ws + 56264000);  //    200,000
    float*    denom = ws + 56464000;               //    200,000
    float*    red   = ws + 56664000;               //         16
    // total ~226.7 MB

    // self-loop preprocessing
    hipMemsetAsync(lpea, 0, (1600000 + 64000) * sizeof(float), stream);
    {
        size_t tot = (size_t)N_EDGES * EDIM;
        deg_loopea_kernel<<<dim3((unsigned)((tot + 255) / 256)), dim3(256), 0, stream>>>(dstp, eattr, lpea, deg);
    }
    {
        size_t tot = (size_t)N_NODES * EDIM;
        loopea_div_kernel<<<dim3((unsigned)((tot + 255) / 256)), dim3(256), 0, stream>>>(lpea, deg);
    }

    // h = relu(x @ w_in + b_in)
    gemm_kernel<<<dim3(HID / 64, (N_NODES + 63) / 64), dim3(256), 0, stream>>>(
        x, w_in, b_in, h, N_NODES, DIN, HID, 1);

    for (int l = 0; l < 2; ++l) {
        hipMemsetAsync(lmaxk, 0, (400000 + 16) * sizeof(float), stream);  // lmaxk+denom+red contiguous
        hipMemsetAsync(accb, 0, (size_t)12800000 * sizeof(float), stream);
        gemm_kernel<<<dim3(HID / 64, (N_NODES + 63) / 64), dim3(256), 0, stream>>>(
            h, wl + (size_t)l * HID * HID, nullptr, xl, N_NODES, HID, HID, 0);
        gemm_kernel<<<dim3(HID / 64, (N_NODES + 63) / 64), dim3(256), 0, stream>>>(
            h, wr + (size_t)l * HID * HID, nullptr, xr, N_NODES, HID, HID, 0);
        edge_logits_kernel<<<dim3(2048), dim3(256), 0, stream>>>(
            xl, xr, eattr, lpea, srcp, dstp,
            we + (size_t)l * EDIM * HID, att + (size_t)l * HID, lgt, lmaxk);
        {
            size_t tot = (size_t)ETOT * HEADS;
            exp_denom_kernel<<<dim3((unsigned)((tot + 255) / 256)), dim3(256), 0, stream>>>(
                dstp, lmaxk, lgt, denom);
        }
        scatter_kernel<<<dim3(4096), dim3(256), 0, stream>>>(xl, lgt, denom, srcp, dstp, accb);
        update_reduce_kernel<<<dim3(N_NODES), dim3(256), 0, stream>>>(
            h, accb, b_conv + (size_t)l * HID, red);
        ln_kernel<<<dim3(N_NODES), dim3(256), 0, stream>>>(
            h, red, ln_w + (size_t)l * HID, ln_b + (size_t)l * HID);
    }

    // out = h @ w_out + b_out
    gemm_kernel<<<dim3(HID / 64, (N_NODES + 63) / 64), dim3(256), 0, stream>>>(
        h, w_out, b_out, (float*)d_out, N_NODES, HID, HID, 0);
}

// Round 2
// 3140.137 us; speedup vs baseline: 3.4159x; 3.4159x over previous
//
#include <hip/hip_runtime.h>
#include <hip/hip_bf16.h>
#include <math.h>

#define N_NODES 50000
#define N_EDGES 800000
#define DIN     384
#define HID     256
#define HEADS   4
#define CDIM    64
#define EDIM    32
#define ETOT    (N_EDGES + N_NODES)   // 850000
#define SLOPE   0.2f
#define LN_EPS  1e-5f

// ================= CSR build (dst-sorted edge index) =================
__global__ void csr_count_kernel(const int* __restrict__ dst, unsigned* __restrict__ cnt) {
    int e = blockIdx.x * 256 + threadIdx.x;
    if (e < N_EDGES) atomicAdd(cnt + dst[e], 1u);
}

// offs[n] = sum_{m<n} (cnt[m]+1)  (+1 = self-loop); offs[N_NODES] = ETOT
__global__ void csr_scan_kernel(const unsigned* __restrict__ cnt, unsigned* __restrict__ offs) {
    __shared__ unsigned partial[1024];
    const int CHUNK = (N_NODES + 1023) / 1024;  // 49
    int t = threadIdx.x;
    int lo = t * CHUNK, hi = min(lo + CHUNK, N_NODES);
    unsigned s = 0;
    for (int i = lo; i < hi; ++i) s += cnt[i] + 1;
    partial[t] = s;
    __syncthreads();
    for (int off = 1; off < 1024; off <<= 1) {
        unsigned v = (t >= off) ? partial[t - off] : 0u;
        __syncthreads();
        partial[t] += v;
        __syncthreads();
    }
    unsigned base = (t == 0) ? 0u : partial[t - 1];
    for (int i = lo; i < hi; ++i) { offs[i] = base; base += cnt[i] + 1; }
    if (t == 1023) offs[N_NODES] = base;
}

// self-loop edge (id N_EDGES+n) goes in slot 0; real edges fill slots 1..deg
__global__ void csr_fill_kernel(const int* __restrict__ dst, const unsigned* __restrict__ offs,
                                unsigned* __restrict__ fill, int* __restrict__ eid) {
    int e = blockIdx.x * 256 + threadIdx.x;
    if (e < N_EDGES) {
        int d = dst[e];
        unsigned p = offs[d] + 1u + atomicAdd(fill + d, 1u);
        eid[p] = e;
    } else if (e < ETOT) {
        int n = e - N_EDGES;
        eid[offs[n]] = e;
    }
}

// ================= loop_ea = mean of incoming edge_attr (CSR, no atomics) ===
__launch_bounds__(256)
__global__ void loopea_csr_kernel(const float* __restrict__ ea, const int* __restrict__ eid,
                                  const unsigned* __restrict__ offs, float* __restrict__ lpea) {
    int wave = threadIdx.x >> 6, lane = threadIdx.x & 63;
    int n = blockIdx.x * 4 + wave;
    unsigned o0 = offs[n], o1 = offs[n + 1];
    int dreal = (int)(o1 - o0) - 1;
    if (lane >= EDIM) return;
    float s = 0.f;
    for (int j = 1; j <= dreal; ++j) {
        int e = eid[o0 + j];
        s += ea[(size_t)e * EDIM + lane];
    }
    lpea[(size_t)n * EDIM + lane] = s / fmaxf((float)dreal, 1.f);
}

// ================= fp32 tiled GEMM: C = act(A@B + bias) =====================
__launch_bounds__(256)
__global__ void gemm_kernel(const float* __restrict__ A, const float* __restrict__ B,
                            const float* __restrict__ bias, float* __restrict__ C,
                            int M, int K, int N, int act) {
    __shared__ float As[16][68];
    __shared__ float Bs[16][68];
    const int tid  = threadIdx.x;
    const int row0 = blockIdx.y * 64;
    const int col0 = blockIdx.x * 64;
    const int tx = tid & 15, ty = tid >> 4;
    const int la_r = tid >> 2;
    const int la_c = (tid & 3) * 4;
    const int lb_r = tid >> 4;
    const int lb_c = (tid & 15) * 4;
    float acc[4][4] = {};

    for (int k0 = 0; k0 < K; k0 += 16) {
        int ar = row0 + la_r;
        float4 av = make_float4(0.f, 0.f, 0.f, 0.f);
        if (ar < M) av = *reinterpret_cast<const float4*>(A + (size_t)ar * K + k0 + la_c);
        As[la_c + 0][la_r] = av.x;
        As[la_c + 1][la_r] = av.y;
        As[la_c + 2][la_r] = av.z;
        As[la_c + 3][la_r] = av.w;
        float4 bv = *reinterpret_cast<const float4*>(B + (size_t)(k0 + lb_r) * N + col0 + lb_c);
        *reinterpret_cast<float4*>(&Bs[lb_r][lb_c]) = bv;
        __syncthreads();
#pragma unroll
        for (int kk = 0; kk < 16; ++kk) {
            float a0 = As[kk][ty * 4 + 0];
            float a1 = As[kk][ty * 4 + 1];
            float a2 = As[kk][ty * 4 + 2];
            float a3 = As[kk][ty * 4 + 3];
            float4 b = *reinterpret_cast<const float4*>(&Bs[kk][tx * 4]);
            acc[0][0] += a0 * b.x; acc[0][1] += a0 * b.y; acc[0][2] += a0 * b.z; acc[0][3] += a0 * b.w;
            acc[1][0] += a1 * b.x; acc[1][1] += a1 * b.y; acc[1][2] += a1 * b.z; acc[1][3] += a1 * b.w;
            acc[2][0] += a2 * b.x; acc[2][1] += a2 * b.y; acc[2][2] += a2 * b.z; acc[2][3] += a2 * b.w;
            acc[3][0] += a3 * b.x; acc[3][1] += a3 * b.y; acc[3][2] += a3 * b.z; acc[3][3] += a3 * b.w;
        }
        __syncthreads();
    }
#pragma unroll
    for (int i = 0; i < 4; ++i) {
        int r = row0 + ty * 4 + i;
        if (r >= M) break;
#pragma unroll
        for (int j = 0; j < 4; ++j) {
            int c = col0 + tx * 4 + j;
            float v = acc[i][j];
            if (bias) v += bias[c];
            if (act) v = fmaxf(v, 0.f);
            C[(size_t)r * N + c] = v;
        }
    }
}

// ================= edge logits (per-edge wave), no atomics ==================
__launch_bounds__(256)
__global__ void edge_logits_kernel(const float* __restrict__ xl, const float* __restrict__ xr,
                                   const float* __restrict__ edge_attr, const float* __restrict__ loop_ea,
                                   const int* __restrict__ src, const int* __restrict__ dst,
                                   const float* __restrict__ we, const float* __restrict__ att,
                                   float* __restrict__ logits) {
    __shared__ float we_s[EDIM][HID];
    __shared__ float att_s[HID];
    for (int i = threadIdx.x; i < EDIM * HID; i += 256) we_s[i >> 8][i & 255] = we[i];
    if (threadIdx.x < HID) att_s[threadIdx.x] = att[threadIdx.x];
    __syncthreads();
    const int lane = threadIdx.x & 63;
    const int wave = threadIdx.x >> 6;
    const int c0   = lane * 4;
    const int head = lane >> 4;
    for (int e = blockIdx.x * 4 + wave; e < ETOT; e += gridDim.x * 4) {
        int s, d;
        float eav = 0.f;
        if (e < N_EDGES) {
            s = src[e]; d = dst[e];
            if (lane < EDIM) eav = edge_attr[(size_t)e * EDIM + lane];
        } else {
            s = e - N_EDGES; d = s;
            if (lane < EDIM) eav = loop_ea[(size_t)s * EDIM + lane];
        }
        float4 ep = make_float4(0.f, 0.f, 0.f, 0.f);
#pragma unroll
        for (int k = 0; k < EDIM; ++k) {
            float a = __shfl(eav, k, 64);
            float4 w4 = *reinterpret_cast<const float4*>(&we_s[k][c0]);
            ep.x += a * w4.x; ep.y += a * w4.y; ep.z += a * w4.z; ep.w += a * w4.w;
        }
        float4 xlv = *reinterpret_cast<const float4*>(xl + (size_t)s * HID + c0);
        float4 xrv = *reinterpret_cast<const float4*>(xr + (size_t)d * HID + c0);
        float m0 = xlv.x + xrv.x + ep.x; m0 = m0 > 0.f ? m0 : SLOPE * m0;
        float m1 = xlv.y + xrv.y + ep.y; m1 = m1 > 0.f ? m1 : SLOPE * m1;
        float m2 = xlv.z + xrv.z + ep.z; m2 = m2 > 0.f ? m2 : SLOPE * m2;
        float m3 = xlv.w + xrv.w + ep.w; m3 = m3 > 0.f ? m3 : SLOPE * m3;
        float part = m0 * att_s[c0] + m1 * att_s[c0 + 1] + m2 * att_s[c0 + 2] + m3 * att_s[c0 + 3];
        part += __shfl_xor(part, 8, 64);
        part += __shfl_xor(part, 4, 64);
        part += __shfl_xor(part, 2, 64);
        part += __shfl_xor(part, 1, 64);
        if ((lane & 15) == 0) logits[(size_t)e * HEADS + head] = part;
    }
}

// ====== per-node: softmax over incoming edges + weighted gather-sum +
//        h += elu(. + b_conv) + LN partial stats (no f32 atomics except 2/block)
__launch_bounds__(256)
__global__ void agg_kernel(const float* __restrict__ xl, const float* __restrict__ logits,
                           const int* __restrict__ src, const int* __restrict__ eid,
                           const unsigned* __restrict__ offs, const float* __restrict__ bconv,
                           float* __restrict__ h, float* __restrict__ red) {
    __shared__ float s_sum[4], s_sq[4];
    const int wave = threadIdx.x >> 6, lane = threadIdx.x & 63;
    const int n = blockIdx.x * 4 + wave;
    const unsigned o0 = offs[n], o1 = offs[n + 1];
    const int dg = (int)(o1 - o0);          // >= 1 (self-loop)

    // pass A: per-head max (head = lane&3, slot = lane>>2)
    const int headA = lane & 3;
    const int slot  = lane >> 2;
    float mx = -1e30f;
    for (int j = slot; j < dg; j += 16) {
        int e = eid[o0 + j];
        mx = fmaxf(mx, logits[(size_t)e * HEADS + headA]);
    }
    mx = fmaxf(mx, __shfl_xor(mx, 4, 64));
    mx = fmaxf(mx, __shfl_xor(mx, 8, 64));
    mx = fmaxf(mx, __shfl_xor(mx, 16, 64));
    mx = fmaxf(mx, __shfl_xor(mx, 32, 64));
    // pass B: per-head denom
    float dn = 0.f;
    for (int j = slot; j < dg; j += 16) {
        int e = eid[o0 + j];
        dn += expf(logits[(size_t)e * HEADS + headA] - mx);
    }
    dn += __shfl_xor(dn, 4, 64);
    dn += __shfl_xor(dn, 8, 64);
    dn += __shfl_xor(dn, 16, 64);
    dn += __shfl_xor(dn, 32, 64);
    // remap: pass C wants head = lane>>4; lanes 0..3 hold heads 0..3
    const int headC = lane >> 4;
    const float mxC  = __shfl(mx, headC, 64);
    const float idnC = 1.f / (__shfl(dn, headC, 64) + 1e-16f);
    const int c0 = lane * 4;
    float4 acc = make_float4(0.f, 0.f, 0.f, 0.f);
    for (int j = 0; j < dg; ++j) {
        int e = eid[o0 + j];
        int s = (e < N_EDGES) ? src[e] : n;
        float alpha = expf(logits[(size_t)e * HEADS + headC] - mxC) * idnC;
        float4 xlv = *reinterpret_cast<const float4*>(xl + (size_t)s * HID + c0);
        acc.x += alpha * xlv.x; acc.y += alpha * xlv.y;
        acc.z += alpha * xlv.z; acc.w += alpha * xlv.w;
    }
    // fused residual + ELU + LN partial stats
    float* hp = h + (size_t)n * HID + c0;
    float4 hv = *reinterpret_cast<const float4*>(hp);
    const float4 bv = *reinterpret_cast<const float4*>(bconv + c0);
    float v0 = acc.x + bv.x; v0 = v0 > 0.f ? v0 : expm1f(v0);
    float v1 = acc.y + bv.y; v1 = v1 > 0.f ? v1 : expm1f(v1);
    float v2 = acc.z + bv.z; v2 = v2 > 0.f ? v2 : expm1f(v2);
    float v3 = acc.w + bv.w; v3 = v3 > 0.f ? v3 : expm1f(v3);
    float h0 = hv.x + v0, h1 = hv.y + v1, h2 = hv.z + v2, h3 = hv.w + v3;
    *reinterpret_cast<float4*>(hp) = make_float4(h0, h1, h2, h3);
    float sm = h0 + h1 + h2 + h3;
    float sq = h0 * h0 + h1 * h1 + h2 * h2 + h3 * h3;
#pragma unroll
    for (int o = 32; o; o >>= 1) {
        sm += __shfl_down(sm, o, 64);
        sq += __shfl_down(sq, o, 64);
    }
    if (lane == 0) { s_sum[wave] = sm; s_sq[wave] = sq; }
    __syncthreads();
    if (threadIdx.x == 0) {
        atomicAdd(red + 0, s_sum[0] + s_sum[1] + s_sum[2] + s_sum[3]);
        atomicAdd(red + 1, s_sq[0] + s_sq[1] + s_sq[2] + s_sq[3]);
    }
}

// ================= graph layernorm apply ====================================
__global__ void ln_kernel(float* __restrict__ h, const float* __restrict__ red,
                          const float* __restrict__ lnw, const float* __restrict__ lnb) {
    size_t i = (size_t)blockIdx.x * 256 + threadIdx.x;
    int col = (int)(i & 255);
    const float inv_cnt = 1.f / (float)((size_t)N_NODES * HID);
    float mu = red[0] * inv_cnt;
    float ms = red[1] * inv_cnt - mu * mu;
    float stdv = sqrtf(fmaxf(ms, 0.f));
    float sc = 1.f / (stdv + LN_EPS);
    h[i] = (h[i] - mu) * sc * lnw[col] + lnb[col];
}

extern "C" void kernel_launch(void* const* d_in, const int* in_sizes, int n_in,
                              void* d_out, int out_size, void* d_ws, size_t ws_size,
                              hipStream_t stream) {
    (void)in_sizes; (void)n_in; (void)out_size; (void)ws_size;
    const float* x      = (const float*)d_in[0];
    const int*   ei     = (const int*)d_in[1];
    const float* eattr  = (const float*)d_in[2];
    const float* w_in   = (const float*)d_in[3];
    const float* b_in   = (const float*)d_in[4];
    const float* wl     = (const float*)d_in[5];
    const float* wr     = (const float*)d_in[6];
    const float* we     = (const float*)d_in[7];
    const float* att    = (const float*)d_in[8];
    const float* b_conv = (const float*)d_in[9];
    const float* ln_w   = (const float*)d_in[10];
    const float* ln_b   = (const float*)d_in[11];
    const float* w_out  = (const float*)d_in[12];
    const float* b_out  = (const float*)d_in[13];
    const int* srcp = ei;
    const int* dstp = ei + N_EDGES;

    float* ws = (float*)d_ws;
    float*    h     = ws;                          // 12,800,000
    float*    xl    = ws + 12800000;               // 12,800,000
    float*    xr    = ws + 25600000;               // 12,800,000
    float*    lpea  = ws + 38400000;               //  1,600,000
    float*    lgt   = ws + 40000000;               //  3,400,000
    unsigned* cnt   = (unsigned*)(ws + 43400000);  //     50,000
    unsigned* offs  = (unsigned*)(ws + 43450000);  //     50,002 (pad)
    unsigned* fill  = (unsigned*)(ws + 43500002);  //     50,000
    int*      eid   = (int*)(ws + 43550002);       //    850,000
    float*    red   = ws + 44400002;               //          2
    // total ~177.6 MB

    // ---- CSR build (once; reused by both layers) ----
    hipMemsetAsync(cnt, 0, 100000 * sizeof(unsigned), stream);   // cnt .. offs head ok? no: cnt only
    hipMemsetAsync(fill, 0, 50000 * sizeof(unsigned), stream);
    csr_count_kernel<<<dim3((N_EDGES + 255) / 256), dim3(256), 0, stream>>>(dstp, cnt);
    csr_scan_kernel<<<dim3(1), dim3(1024), 0, stream>>>(cnt, offs);
    csr_fill_kernel<<<dim3((ETOT + 255) / 256), dim3(256), 0, stream>>>(dstp, offs, fill, eid);
    loopea_csr_kernel<<<dim3(N_NODES / 4), dim3(256), 0, stream>>>(eattr, eid, offs, lpea);

    // h = relu(x @ w_in + b_in)
    gemm_kernel<<<dim3(HID / 64, (N_NODES + 63) / 64), dim3(256), 0, stream>>>(
        x, w_in, b_in, h, N_NODES, DIN, HID, 1);

    for (int l = 0; l < 2; ++l) {
        hipMemsetAsync(red, 0, 2 * sizeof(float), stream);
        gemm_kernel<<<dim3(HID / 64, (N_NODES + 63) / 64), dim3(256), 0, stream>>>(
            h, wl + (size_t)l * HID * HID, nullptr, xl, N_NODES, HID, HID, 0);
        gemm_kernel<<<dim3(HID / 64, (N_NODES + 63) / 64), dim3(256), 0, stream>>>(
            h, wr + (size_t)l * HID * HID, nullptr, xr, N_NODES, HID, HID, 0);
        edge_logits_kernel<<<dim3(2048), dim3(256), 0, stream>>>(
            xl, xr, eattr, lpea, srcp, dstp,
            we + (size_t)l * EDIM * HID, att + (size_t)l * HID, lgt);
        agg_kernel<<<dim3(N_NODES / 4), dim3(256), 0, stream>>>(
            xl, lgt, srcp, eid, offs, b_conv + (size_t)l * HID, h, red);
        ln_kernel<<<dim3(N_NODES), dim3(256), 0, stream>>>(
            h, red, ln_w + (size_t)l * HID, ln_b + (size_t)l * HID);
    }

    // out = h @ w_out + b_out
    gemm_kernel<<<dim3(HID / 64, (N_NODES + 63) / 64), dim3(256), 0, stream>>>(
        h, w_out, b_out, (float*)d_out, N_NODES, HID, HID, 0);
}

// Round 3
// 2208.192 us; speedup vs baseline: 4.8575x; 1.4220x over previous
//
#include <hip/hip_runtime.h>
#include <hip/hip_bf16.h>
#include <math.h>

#define N_NODES 50000
#define N_EDGES 800000
#define DIN     384
#define HID     256
#define HEADS   4
#define EDIM    32
#define ETOT    (N_EDGES + N_NODES)   // 850000
#define SLOPE   0.2f
#define LN_EPS  1e-5f

typedef short short8 __attribute__((ext_vector_type(8)));
typedef float f32x4  __attribute__((ext_vector_type(4)));

__device__ __forceinline__ unsigned short f2b(float f) {
    unsigned u = __float_as_uint(f);
    return (unsigned short)((u + 0x7fffu + ((u >> 16) & 1u)) >> 16);  // RNE
}
__device__ __forceinline__ float b2f(unsigned short s) {
    return __uint_as_float((unsigned)s << 16);
}

// ================= CSR build (dst-sorted edge index) =================
__global__ void csr_count_kernel(const int* __restrict__ dst, unsigned* __restrict__ cnt) {
    int e = blockIdx.x * 256 + threadIdx.x;
    if (e < N_EDGES) atomicAdd(cnt + dst[e], 1u);
}

__global__ void csr_scan_kernel(const unsigned* __restrict__ cnt, unsigned* __restrict__ offs) {
    __shared__ unsigned partial[1024];
    const int CHUNK = (N_NODES + 1023) / 1024;  // 49
    int t = threadIdx.x;
    int lo = t * CHUNK, hi = min(lo + CHUNK, N_NODES);
    unsigned s = 0;
    for (int i = lo; i < hi; ++i) s += cnt[i] + 1;
    partial[t] = s;
    __syncthreads();
    for (int off = 1; off < 1024; off <<= 1) {
        unsigned v = (t >= off) ? partial[t - off] : 0u;
        __syncthreads();
        partial[t] += v;
        __syncthreads();
    }
    unsigned base = (t == 0) ? 0u : partial[t - 1];
    for (int i = lo; i < hi; ++i) { offs[i] = base; base += cnt[i] + 1; }
    if (t == 1023) offs[N_NODES] = base;
}

__global__ void csr_fill_kernel(const int* __restrict__ dst, const unsigned* __restrict__ offs,
                                unsigned* __restrict__ fill, int* __restrict__ eid) {
    int e = blockIdx.x * 256 + threadIdx.x;
    if (e < N_EDGES) {
        int d = dst[e];
        unsigned p = offs[d] + 1u + atomicAdd(fill + d, 1u);
        eid[p] = e;
    } else if (e < ETOT) {
        int n = e - N_EDGES;
        eid[offs[n]] = e;
    }
}

// ================= loop_ea = mean of incoming edge_attr (CSR) ===============
__launch_bounds__(256)
__global__ void loopea_csr_kernel(const float* __restrict__ ea, const int* __restrict__ eid,
                                  const unsigned* __restrict__ offs, float* __restrict__ lpea) {
    int wave = threadIdx.x >> 6, lane = threadIdx.x & 63;
    int n = blockIdx.x * 4 + wave;
    unsigned o0 = offs[n], o1 = offs[n + 1];
    int dreal = (int)(o1 - o0) - 1;
    if (lane >= EDIM) return;
    float s = 0.f;
    for (int j = 1; j <= dreal; ++j) {
        int e = eid[o0 + j];
        s += ea[(size_t)e * EDIM + lane];
    }
    lpea[(size_t)n * EDIM + lane] = s / fmaxf((float)dreal, 1.f);
}

// ================= weight convert + transpose: T[c][k] = bf16(W[k][c]) ======
// W is [K x 256] row-major; total = K*256
__global__ void cvt_wT_kernel(const float* __restrict__ W, unsigned short* __restrict__ T,
                              int total, int K) {
    int i = blockIdx.x * 256 + threadIdx.x;
    if (i >= total) return;
    int k = i >> 8, c = i & 255;
    T[c * K + k] = f2b(W[i]);
}

// ================= bf16 MFMA GEMM: C = act(A @ BT^T + bias) =================
// A [M x K] (f32 or bf16), BT [256 cols][K] bf16. N = 256. K multiple of 32.
// Block = 64 rows x 256 cols; wave w: rows w*16..w*16+15.
template<bool A_F32, bool RELU, bool OUT_F32, bool OUT_BF16>
__launch_bounds__(256, 2)
__global__ void mfma_gemm_kernel(const void* __restrict__ Av, const unsigned short* __restrict__ BT,
                                 const float* __restrict__ bias,
                                 float* __restrict__ Cf, unsigned short* __restrict__ Cb,
                                 int M, int K) {
    const int w = threadIdx.x >> 6, l = threadIdx.x & 63;
    const int l15 = l & 15, q = l >> 4;
    const int row  = blockIdx.x * 64 + w * 16 + l15;   // A-frag row (lane)
    const int rowc = min(row, M - 1);
    f32x4 acc[16];
#pragma unroll
    for (int t = 0; t < 16; ++t) acc[t] = (f32x4){0.f, 0.f, 0.f, 0.f};

    for (int k0 = 0; k0 < K; k0 += 32) {
        short8 af;
        if (A_F32) {
            const float* ap = (const float*)Av + (size_t)rowc * K + k0 + q * 8;
            float4 a0 = *(const float4*)ap;
            float4 a1 = *(const float4*)(ap + 4);
            af[0] = (short)f2b(a0.x); af[1] = (short)f2b(a0.y);
            af[2] = (short)f2b(a0.z); af[3] = (short)f2b(a0.w);
            af[4] = (short)f2b(a1.x); af[5] = (short)f2b(a1.y);
            af[6] = (short)f2b(a1.z); af[7] = (short)f2b(a1.w);
        } else {
            af = *(const short8*)((const unsigned short*)Av + (size_t)rowc * K + k0 + q * 8);
        }
#pragma unroll
        for (int t = 0; t < 16; ++t) {
            short8 bf = *(const short8*)(BT + (size_t)(t * 16 + l15) * K + k0 + q * 8);
            acc[t] = __builtin_amdgcn_mfma_f32_16x16x32_bf16(af, bf, acc[t], 0, 0, 0);
        }
    }
    const int r0 = blockIdx.x * 64 + w * 16 + q * 4;   // D rows
#pragma unroll
    for (int t = 0; t < 16; ++t) {
        int col = t * 16 + l15;
        float bv = bias ? bias[col] : 0.f;
#pragma unroll
        for (int r = 0; r < 4; ++r) {
            int rr = r0 + r;
            if (rr >= M) break;
            float v = acc[t][r] + bv;
            if (RELU) v = fmaxf(v, 0.f);
            if (OUT_F32) Cf[(size_t)rr * 256 + col] = v;
            if (OUT_BF16) Cb[(size_t)rr * 256 + col] = f2b(v);
        }
    }
}

// ================= edge logits via per-wave MFMA ============================
// Wave handles 16 consecutive edges: ep[16x256] = ea2[16x32] @ we[32x256] via
// 16 MFMAs, redistributed through swizzled per-wave LDS, then leaky+att dot.
__launch_bounds__(256, 4)
__global__ void edge_mfma_kernel(const float* __restrict__ ea, const float* __restrict__ lpea,
                                 const unsigned short* __restrict__ xl,
                                 const unsigned short* __restrict__ xr,
                                 const int* __restrict__ src, const int* __restrict__ dst,
                                 const unsigned short* __restrict__ weT,
                                 const float* __restrict__ att,
                                 float* __restrict__ lgt) {
    __shared__ unsigned short eplds[4][256][18];   // [wave][col][edge(swz) pad]
    const int w = threadIdx.x >> 6, l = threadIdx.x & 63;
    const int l15 = l & 15, q = l >> 4;
    const int ebase = blockIdx.x * 64 + w * 16;

    // ---- MFMA phase ----
    {
        int e = min(ebase + l15, ETOT - 1);
        const float* ap = (e < N_EDGES) ? (ea + (size_t)e * EDIM)
                                        : (lpea + (size_t)(e - N_EDGES) * EDIM);
        ap += q * 8;
        float4 a0 = *(const float4*)ap;
        float4 a1 = *(const float4*)(ap + 4);
        short8 af;
        af[0] = (short)f2b(a0.x); af[1] = (short)f2b(a0.y);
        af[2] = (short)f2b(a0.z); af[3] = (short)f2b(a0.w);
        af[4] = (short)f2b(a1.x); af[5] = (short)f2b(a1.y);
        af[6] = (short)f2b(a1.z); af[7] = (short)f2b(a1.w);
#pragma unroll
        for (int t = 0; t < 16; ++t) {
            short8 bf = *(const short8*)(weT + (size_t)(t * 16 + l15) * EDIM + q * 8);
            f32x4 dd = (f32x4){0.f, 0.f, 0.f, 0.f};
            dd = __builtin_amdgcn_mfma_f32_16x16x32_bf16(af, bf, dd, 0, 0, 0);
            int c  = t * 16 + l15;
            int js = (q * 4) ^ ((c >> 2) & 12);     // swizzle edge-index bits 2:3
            unsigned v0 = (unsigned)f2b(dd[0]) | ((unsigned)f2b(dd[1]) << 16);
            unsigned v1 = (unsigned)f2b(dd[2]) | ((unsigned)f2b(dd[3]) << 16);
            unsigned short* p = &eplds[w][c][js];
            *(unsigned*)(p)     = v0;
            *(unsigned*)(p + 2) = v1;
        }
    }
    // per-wave LDS only: compiler-inserted lgkmcnt orders write->read within wave

    // ---- per-edge logit phase: lane covers channels l*4..l*4+3, head = q ----
    const float4 attv = *(const float4*)(att + l * 4);
    const int swz = l & 12;   // (c>>2)&12 with c = l*4+i  ->  l&12
    for (int j = 0; j < 16; ++j) {
        int e = ebase + j;
        if (e >= ETOT) break;
        int s, d;
        if (e < N_EDGES) { s = src[e]; d = dst[e]; }
        else             { s = e - N_EDGES; d = s; }
        int jj = j ^ swz;
        float ep0 = b2f(eplds[w][l * 4 + 0][jj]);
        float ep1 = b2f(eplds[w][l * 4 + 1][jj]);
        float ep2 = b2f(eplds[w][l * 4 + 2][jj]);
        float ep3 = b2f(eplds[w][l * 4 + 3][jj]);
        ushort4 xlv = *(const ushort4*)(xl + (size_t)s * 256 + l * 4);
        ushort4 xrv = *(const ushort4*)(xr + (size_t)d * 256 + l * 4);
        float m0 = b2f(xlv.x) + b2f(xrv.x) + ep0; m0 = m0 > 0.f ? m0 : SLOPE * m0;
        float m1 = b2f(xlv.y) + b2f(xrv.y) + ep1; m1 = m1 > 0.f ? m1 : SLOPE * m1;
        float m2 = b2f(xlv.z) + b2f(xrv.z) + ep2; m2 = m2 > 0.f ? m2 : SLOPE * m2;
        float m3 = b2f(xlv.w) + b2f(xrv.w) + ep3; m3 = m3 > 0.f ? m3 : SLOPE * m3;
        float part = m0 * attv.x + m1 * attv.y + m2 * attv.z + m3 * attv.w;
        part += __shfl_xor(part, 1, 64);
        part += __shfl_xor(part, 2, 64);
        part += __shfl_xor(part, 4, 64);
        part += __shfl_xor(part, 8, 64);
        if (l15 == 0) lgt[(size_t)e * HEADS + q] = part;
    }
}

// ====== per-node: softmax + weighted gather-sum + h += elu(.) + LN stats ====
__launch_bounds__(256)
__global__ void agg_kernel(const unsigned short* __restrict__ xl, const float* __restrict__ logits,
                           const int* __restrict__ src, const int* __restrict__ eid,
                           const unsigned* __restrict__ offs, const float* __restrict__ bconv,
                           float* __restrict__ h, float* __restrict__ red) {
    __shared__ float s_sum[4], s_sq[4];
    const int wave = threadIdx.x >> 6, lane = threadIdx.x & 63;
    const int n = blockIdx.x * 4 + wave;
    const unsigned o0 = offs[n], o1 = offs[n + 1];
    const int dg = (int)(o1 - o0);

    const int headA = lane & 3;
    const int slot  = lane >> 2;
    float mx = -1e30f;
    for (int j = slot; j < dg; j += 16) {
        int e = eid[o0 + j];
        mx = fmaxf(mx, logits[(size_t)e * HEADS + headA]);
    }
    mx = fmaxf(mx, __shfl_xor(mx, 4, 64));
    mx = fmaxf(mx, __shfl_xor(mx, 8, 64));
    mx = fmaxf(mx, __shfl_xor(mx, 16, 64));
    mx = fmaxf(mx, __shfl_xor(mx, 32, 64));
    float dn = 0.f;
    for (int j = slot; j < dg; j += 16) {
        int e = eid[o0 + j];
        dn += expf(logits[(size_t)e * HEADS + headA] - mx);
    }
    dn += __shfl_xor(dn, 4, 64);
    dn += __shfl_xor(dn, 8, 64);
    dn += __shfl_xor(dn, 16, 64);
    dn += __shfl_xor(dn, 32, 64);
    const int headC = lane >> 4;
    const float mxC  = __shfl(mx, headC, 64);
    const float idnC = 1.f / (__shfl(dn, headC, 64) + 1e-16f);
    const int c0 = lane * 4;
    float4 acc = make_float4(0.f, 0.f, 0.f, 0.f);
    for (int j = 0; j < dg; ++j) {
        int e = eid[o0 + j];
        int s = (e < N_EDGES) ? src[e] : n;
        float alpha = expf(logits[(size_t)e * HEADS + headC] - mxC) * idnC;
        ushort4 xlv = *(const ushort4*)(xl + (size_t)s * 256 + c0);
        acc.x += alpha * b2f(xlv.x); acc.y += alpha * b2f(xlv.y);
        acc.z += alpha * b2f(xlv.z); acc.w += alpha * b2f(xlv.w);
    }
    float* hp = h + (size_t)n * HID + c0;
    float4 hv = *reinterpret_cast<const float4*>(hp);
    const float4 bv = *reinterpret_cast<const float4*>(bconv + c0);
    float v0 = acc.x + bv.x; v0 = v0 > 0.f ? v0 : expm1f(v0);
    float v1 = acc.y + bv.y; v1 = v1 > 0.f ? v1 : expm1f(v1);
    float v2 = acc.z + bv.z; v2 = v2 > 0.f ? v2 : expm1f(v2);
    float v3 = acc.w + bv.w; v3 = v3 > 0.f ? v3 : expm1f(v3);
    float h0 = hv.x + v0, h1 = hv.y + v1, h2 = hv.z + v2, h3 = hv.w + v3;
    *reinterpret_cast<float4*>(hp) = make_float4(h0, h1, h2, h3);
    float sm = h0 + h1 + h2 + h3;
    float sq = h0 * h0 + h1 * h1 + h2 * h2 + h3 * h3;
#pragma unroll
    for (int o = 32; o; o >>= 1) {
        sm += __shfl_down(sm, o, 64);
        sq += __shfl_down(sq, o, 64);
    }
    if (lane == 0) { s_sum[wave] = sm; s_sq[wave] = sq; }
    __syncthreads();
    if (threadIdx.x == 0) {
        atomicAdd(red + 0, s_sum[0] + s_sum[1] + s_sum[2] + s_sum[3]);
        atomicAdd(red + 1, s_sq[0] + s_sq[1] + s_sq[2] + s_sq[3]);
    }
}

// ================= graph layernorm apply (writes f32 + bf16) ================
__global__ void ln_kernel(float* __restrict__ h, unsigned short* __restrict__ hb,
                          const float* __restrict__ red,
                          const float* __restrict__ lnw, const float* __restrict__ lnb) {
    size_t i = (size_t)blockIdx.x * 256 + threadIdx.x;
    int col = (int)(i & 255);
    const float inv_cnt = 1.f / (float)((size_t)N_NODES * HID);
    float mu = red[0] * inv_cnt;
    float ms = red[1] * inv_cnt - mu * mu;
    float stdv = sqrtf(fmaxf(ms, 0.f));
    float sc = 1.f / (stdv + LN_EPS);
    float v = (h[i] - mu) * sc * lnw[col] + lnb[col];
    h[i] = v;
    hb[i] = f2b(v);
}

extern "C" void kernel_launch(void* const* d_in, const int* in_sizes, int n_in,
                              void* d_out, int out_size, void* d_ws, size_t ws_size,
                              hipStream_t stream) {
    (void)in_sizes; (void)n_in; (void)out_size; (void)ws_size;
    const float* x      = (const float*)d_in[0];
    const int*   ei     = (const int*)d_in[1];
    const float* eattr  = (const float*)d_in[2];
    const float* w_in   = (const float*)d_in[3];
    const float* b_in   = (const float*)d_in[4];
    const float* wl     = (const float*)d_in[5];
    const float* wr     = (const float*)d_in[6];
    const float* we     = (const float*)d_in[7];
    const float* att    = (const float*)d_in[8];
    const float* b_conv = (const float*)d_in[9];
    const float* ln_w   = (const float*)d_in[10];
    const float* ln_b   = (const float*)d_in[11];
    const float* w_out  = (const float*)d_in[12];
    const float* b_out  = (const float*)d_in[13];
    const int* srcp = ei;
    const int* dstp = ei + N_EDGES;

    float* ws = (float*)d_ws;
    float*          h    = ws;                                  // 12,800,000 f32
    unsigned short* hb   = (unsigned short*)(ws + 12800000);    //  6,400,000 w
    unsigned short* xl   = (unsigned short*)(ws + 19200000);    //  6,400,000 w
    unsigned short* xr   = (unsigned short*)(ws + 25600000);    //  6,400,000 w
    float*          lpea = ws + 32000000;                       //  1,600,000
    float*          lgt  = ws + 33600000;                       //  3,400,000
    unsigned short* wT   = (unsigned short*)(ws + 37000000);    //    222,000 w
    unsigned*       cnt  = (unsigned*)(ws + 37222000);          //     50,000
    unsigned*       offs = (unsigned*)(ws + 37272000);          //     50,002
    unsigned*       fill = (unsigned*)(ws + 37322002);          //     50,000
    int*            eid  = (int*)(ws + 37372002);               //    850,000
    float*          red  = ws + 38222002;                       //          2
    // total ~152.9 MB

    unsigned short* w_inT  = wT;            // [256][384]
    unsigned short* wlT0   = wT + 98304;    // [256][256]
    unsigned short* wlT1   = wT + 163840;
    unsigned short* wrT0   = wT + 229376;
    unsigned short* wrT1   = wT + 294912;
    unsigned short* w_outT = wT + 360448;
    unsigned short* weT0   = wT + 425984;   // [256][32]
    unsigned short* weT1   = wT + 434176;

    // ---- CSR build ----
    hipMemsetAsync(cnt, 0, 50000 * sizeof(unsigned), stream);
    hipMemsetAsync(fill, 0, 50000 * sizeof(unsigned), stream);
    csr_count_kernel<<<dim3((N_EDGES + 255) / 256), dim3(256), 0, stream>>>(dstp, cnt);
    csr_scan_kernel<<<dim3(1), dim3(1024), 0, stream>>>(cnt, offs);
    csr_fill_kernel<<<dim3((ETOT + 255) / 256), dim3(256), 0, stream>>>(dstp, offs, fill, eid);
    loopea_csr_kernel<<<dim3(N_NODES / 4), dim3(256), 0, stream>>>(eattr, eid, offs, lpea);

    // ---- weight conversion/transpose ----
    cvt_wT_kernel<<<dim3(384), dim3(256), 0, stream>>>(w_in, w_inT, 98304, 384);
    cvt_wT_kernel<<<dim3(256), dim3(256), 0, stream>>>(wl, wlT0, 65536, 256);
    cvt_wT_kernel<<<dim3(256), dim3(256), 0, stream>>>(wl + 65536, wlT1, 65536, 256);
    cvt_wT_kernel<<<dim3(256), dim3(256), 0, stream>>>(wr, wrT0, 65536, 256);
    cvt_wT_kernel<<<dim3(256), dim3(256), 0, stream>>>(wr + 65536, wrT1, 65536, 256);
    cvt_wT_kernel<<<dim3(256), dim3(256), 0, stream>>>(w_out, w_outT, 65536, 256);
    cvt_wT_kernel<<<dim3(32), dim3(256), 0, stream>>>(we, weT0, 8192, 32);
    cvt_wT_kernel<<<dim3(32), dim3(256), 0, stream>>>(we + 8192, weT1, 8192, 32);

    const int GB = (N_NODES + 63) / 64;   // 782 blocks for node GEMMs

    // h = relu(x @ w_in + b_in)  -> h (f32) + hb (bf16)
    mfma_gemm_kernel<true, true, true, true><<<dim3(GB), dim3(256), 0, stream>>>(
        x, w_inT, b_in, h, hb, N_NODES, DIN);

    for (int l = 0; l < 2; ++l) {
        hipMemsetAsync(red, 0, 2 * sizeof(float), stream);
        const unsigned short* wlT = l ? wlT1 : wlT0;
        const unsigned short* wrT = l ? wrT1 : wrT0;
        const unsigned short* weT = l ? weT1 : weT0;
        mfma_gemm_kernel<false, false, false, true><<<dim3(GB), dim3(256), 0, stream>>>(
            hb, wlT, nullptr, nullptr, xl, N_NODES, HID);
        mfma_gemm_kernel<false, false, false, true><<<dim3(GB), dim3(256), 0, stream>>>(
            hb, wrT, nullptr, nullptr, xr, N_NODES, HID);
        edge_mfma_kernel<<<dim3((ETOT + 63) / 64), dim3(256), 0, stream>>>(
            eattr, lpea, xl, xr, srcp, dstp, weT, att + (size_t)l * HID, lgt);
        agg_kernel<<<dim3(N_NODES / 4), dim3(256), 0, stream>>>(
            xl, lgt, srcp, eid, offs, b_conv + (size_t)l * HID, h, red);
        ln_kernel<<<dim3(N_NODES), dim3(256), 0, stream>>>(
            h, hb, red, ln_w + (size_t)l * HID, ln_b + (size_t)l * HID);
    }

    // out = h @ w_out + b_out (f32)
    mfma_gemm_kernel<false, false, true, false><<<dim3(GB), dim3(256), 0, stream>>>(
        hb, w_outT, b_out, (float*)d_out, nullptr, N_NODES, HID);
}

// Round 4
// 2026.132 us; speedup vs baseline: 5.2940x; 1.0899x over previous
//
#include <hip/hip_runtime.h>
#include <hip/hip_bf16.h>
#include <math.h>

#define N_NODES 50000
#define N_EDGES 800000
#define DIN     384
#define HID     256
#define HEADS   4
#define EDIM    32
#define ETOT    (N_EDGES + N_NODES)   // 850000
#define SLOPE   0.2f
#define LN_EPS  1e-5f

typedef short short8 __attribute__((ext_vector_type(8)));
typedef float f32x4  __attribute__((ext_vector_type(4)));

__device__ __forceinline__ unsigned short f2b(float f) {
    unsigned u = __float_as_uint(f);
    return (unsigned short)((u + 0x7fffu + ((u >> 16) & 1u)) >> 16);  // RNE
}
__device__ __forceinline__ float b2f(unsigned short s) {
    return __uint_as_float((unsigned)s << 16);
}

// ================= CSR build (dst-sorted edge index) =================
__global__ void csr_count_kernel(const int* __restrict__ dst, unsigned* __restrict__ cnt) {
    int e = blockIdx.x * 256 + threadIdx.x;
    if (e < N_EDGES) atomicAdd(cnt + dst[e], 1u);
}

__global__ void csr_scan_kernel(const unsigned* __restrict__ cnt, unsigned* __restrict__ offs) {
    __shared__ unsigned partial[1024];
    const int CHUNK = (N_NODES + 1023) / 1024;  // 49
    int t = threadIdx.x;
    int lo = t * CHUNK, hi = min(lo + CHUNK, N_NODES);
    unsigned s = 0;
    for (int i = lo; i < hi; ++i) s += cnt[i] + 1;
    partial[t] = s;
    __syncthreads();
    for (int off = 1; off < 1024; off <<= 1) {
        unsigned v = (t >= off) ? partial[t - off] : 0u;
        __syncthreads();
        partial[t] += v;
        __syncthreads();
    }
    unsigned base = (t == 0) ? 0u : partial[t - 1];
    for (int i = lo; i < hi; ++i) { offs[i] = base; base += cnt[i] + 1; }
    if (t == 1023) offs[N_NODES] = base;
}

__global__ void csr_fill_kernel(const int* __restrict__ dst, const unsigned* __restrict__ offs,
                                unsigned* __restrict__ fill, int* __restrict__ eid) {
    int e = blockIdx.x * 256 + threadIdx.x;
    if (e < N_EDGES) {
        int d = dst[e];
        unsigned p = offs[d] + 1u + atomicAdd(fill + d, 1u);
        eid[p] = e;
    } else if (e < ETOT) {
        int n = e - N_EDGES;
        eid[offs[n]] = e;
    }
}

// ================= loop_ea = mean of incoming edge_attr (CSR) ===============
__launch_bounds__(256)
__global__ void loopea_csr_kernel(const float* __restrict__ ea, const int* __restrict__ eid,
                                  const unsigned* __restrict__ offs, float* __restrict__ lpea) {
    int wave = threadIdx.x >> 6, lane = threadIdx.x & 63;
    int n = blockIdx.x * 4 + wave;
    unsigned o0 = offs[n], o1 = offs[n + 1];
    int dreal = (int)(o1 - o0) - 1;
    if (lane >= EDIM) return;
    float s = 0.f;
    for (int j = 1; j <= dreal; ++j) {
        int e = eid[o0 + j];
        s += ea[(size_t)e * EDIM + lane];
    }
    lpea[(size_t)n * EDIM + lane] = s / fmaxf((float)dreal, 1.f);
}

// ================= weight convert + transpose: T[c][k] = bf16(W[k][c]) ======
__global__ void cvt_wT_kernel(const float* __restrict__ W, unsigned short* __restrict__ T,
                              int total, int K) {
    int i = blockIdx.x * 256 + threadIdx.x;
    if (i >= total) return;
    int k = i >> 8, c = i & 255;
    T[c * K + k] = f2b(W[i]);
}

// ================= bf16 MFMA GEMM: C = act(A @ BT^T + bias) =================
template<bool A_F32, bool RELU, bool OUT_F32, bool OUT_BF16>
__launch_bounds__(256, 2)
__global__ void mfma_gemm_kernel(const void* __restrict__ Av, const unsigned short* __restrict__ BT,
                                 const float* __restrict__ bias,
                                 float* __restrict__ Cf, unsigned short* __restrict__ Cb,
                                 int M, int K) {
    const int w = threadIdx.x >> 6, l = threadIdx.x & 63;
    const int l15 = l & 15, q = l >> 4;
    const int row  = blockIdx.x * 64 + w * 16 + l15;
    const int rowc = min(row, M - 1);
    f32x4 acc[16];
#pragma unroll
    for (int t = 0; t < 16; ++t) acc[t] = (f32x4){0.f, 0.f, 0.f, 0.f};

    for (int k0 = 0; k0 < K; k0 += 32) {
        short8 af;
        if (A_F32) {
            const float* ap = (const float*)Av + (size_t)rowc * K + k0 + q * 8;
            float4 a0 = *(const float4*)ap;
            float4 a1 = *(const float4*)(ap + 4);
            af[0] = (short)f2b(a0.x); af[1] = (short)f2b(a0.y);
            af[2] = (short)f2b(a0.z); af[3] = (short)f2b(a0.w);
            af[4] = (short)f2b(a1.x); af[5] = (short)f2b(a1.y);
            af[6] = (short)f2b(a1.z); af[7] = (short)f2b(a1.w);
        } else {
            af = *(const short8*)((const unsigned short*)Av + (size_t)rowc * K + k0 + q * 8);
        }
#pragma unroll
        for (int t = 0; t < 16; ++t) {
            short8 bf = *(const short8*)(BT + (size_t)(t * 16 + l15) * K + k0 + q * 8);
            acc[t] = __builtin_amdgcn_mfma_f32_16x16x32_bf16(af, bf, acc[t], 0, 0, 0);
        }
    }
    const int r0 = blockIdx.x * 64 + w * 16 + q * 4;
#pragma unroll
    for (int t = 0; t < 16; ++t) {
        int col = t * 16 + l15;
        float bv = bias ? bias[col] : 0.f;
#pragma unroll
        for (int r = 0; r < 4; ++r) {
            int rr = r0 + r;
            if (rr >= M) break;
            float v = acc[t][r] + bv;
            if (RELU) v = fmaxf(v, 0.f);
            if (OUT_F32) Cf[(size_t)rr * 256 + col] = v;
            if (OUT_BF16) Cb[(size_t)rr * 256 + col] = f2b(v);
        }
    }
}

// ================= edge logits via per-wave MFMA ============================
__launch_bounds__(256, 3)
__global__ void edge_mfma_kernel(const float* __restrict__ ea, const float* __restrict__ lpea,
                                 const unsigned short* __restrict__ xl,
                                 const unsigned short* __restrict__ xr,
                                 const int* __restrict__ src, const int* __restrict__ dst,
                                 const unsigned short* __restrict__ weT,
                                 const float* __restrict__ att,
                                 float* __restrict__ lgt) {
    __shared__ unsigned short eplds[4][256][18];
    const int w = threadIdx.x >> 6, l = threadIdx.x & 63;
    const int l15 = l & 15, q = l >> 4;
    const int ebase = blockIdx.x * 64 + w * 16;

    // register copy of src/dst for the wave's 16 edges (lane j<16 holds edge ebase+j)
    int sreg, dreg;
    {
        int eL = min(ebase + l15, ETOT - 1);
        if (eL < N_EDGES) { sreg = src[eL]; dreg = dst[eL]; }
        else { sreg = dreg = eL - N_EDGES; }
    }

    // ---- MFMA phase: ep[16x256] = ea2[16x32] @ we ----
    {
        int e = min(ebase + l15, ETOT - 1);
        const float* ap = (e < N_EDGES) ? (ea + (size_t)e * EDIM)
                                        : (lpea + (size_t)(e - N_EDGES) * EDIM);
        ap += q * 8;
        float4 a0 = *(const float4*)ap;
        float4 a1 = *(const float4*)(ap + 4);
        short8 af;
        af[0] = (short)f2b(a0.x); af[1] = (short)f2b(a0.y);
        af[2] = (short)f2b(a0.z); af[3] = (short)f2b(a0.w);
        af[4] = (short)f2b(a1.x); af[5] = (short)f2b(a1.y);
        af[6] = (short)f2b(a1.z); af[7] = (short)f2b(a1.w);
#pragma unroll
        for (int t = 0; t < 16; ++t) {
            short8 bf = *(const short8*)(weT + (size_t)(t * 16 + l15) * EDIM + q * 8);
            f32x4 dd = (f32x4){0.f, 0.f, 0.f, 0.f};
            dd = __builtin_amdgcn_mfma_f32_16x16x32_bf16(af, bf, dd, 0, 0, 0);
            int c  = t * 16 + l15;
            int js = (q * 4) ^ ((c >> 2) & 12);
            unsigned v0 = (unsigned)f2b(dd[0]) | ((unsigned)f2b(dd[1]) << 16);
            unsigned v1 = (unsigned)f2b(dd[2]) | ((unsigned)f2b(dd[3]) << 16);
            unsigned short* p = &eplds[w][c][js];
            *(unsigned*)(p)     = v0;
            *(unsigned*)(p + 2) = v1;
        }
    }

    // ---- per-edge logit phase, unroll 2 ----
    const float4 attv = *(const float4*)(att + l * 4);
    const int swz = l & 12;
    const int nE = min(16, ETOT - ebase);
    for (int j = 0; j < nE; j += 2) {
        const int  e0   = ebase + j;
        const bool hasB = (j + 1) < nE;
        const int  j1   = hasB ? j + 1 : j;
        int s0 = __shfl(sreg, j, 64),  d0 = __shfl(dreg, j, 64);
        int s1 = __shfl(sreg, j1, 64), d1 = __shfl(dreg, j1, 64);
        ushort4 xl0 = *(const ushort4*)(xl + (size_t)s0 * 256 + l * 4);
        ushort4 xr0 = *(const ushort4*)(xr + (size_t)d0 * 256 + l * 4);
        ushort4 xl1 = *(const ushort4*)(xl + (size_t)s1 * 256 + l * 4);
        ushort4 xr1 = *(const ushort4*)(xr + (size_t)d1 * 256 + l * 4);
        int jj0 = j ^ swz, jj1 = j1 ^ swz;
        float m00 = b2f(xl0.x) + b2f(xr0.x) + b2f(eplds[w][l * 4 + 0][jj0]);
        float m01 = b2f(xl0.y) + b2f(xr0.y) + b2f(eplds[w][l * 4 + 1][jj0]);
        float m02 = b2f(xl0.z) + b2f(xr0.z) + b2f(eplds[w][l * 4 + 2][jj0]);
        float m03 = b2f(xl0.w) + b2f(xr0.w) + b2f(eplds[w][l * 4 + 3][jj0]);
        float m10 = b2f(xl1.x) + b2f(xr1.x) + b2f(eplds[w][l * 4 + 0][jj1]);
        float m11 = b2f(xl1.y) + b2f(xr1.y) + b2f(eplds[w][l * 4 + 1][jj1]);
        float m12 = b2f(xl1.z) + b2f(xr1.z) + b2f(eplds[w][l * 4 + 2][jj1]);
        float m13 = b2f(xl1.w) + b2f(xr1.w) + b2f(eplds[w][l * 4 + 3][jj1]);
        m00 = m00 > 0.f ? m00 : SLOPE * m00;  m01 = m01 > 0.f ? m01 : SLOPE * m01;
        m02 = m02 > 0.f ? m02 : SLOPE * m02;  m03 = m03 > 0.f ? m03 : SLOPE * m03;
        m10 = m10 > 0.f ? m10 : SLOPE * m10;  m11 = m11 > 0.f ? m11 : SLOPE * m11;
        m12 = m12 > 0.f ? m12 : SLOPE * m12;  m13 = m13 > 0.f ? m13 : SLOPE * m13;
        float p0 = m00 * attv.x + m01 * attv.y + m02 * attv.z + m03 * attv.w;
        float p1 = m10 * attv.x + m11 * attv.y + m12 * attv.z + m13 * attv.w;
        p0 += __shfl_xor(p0, 1, 64);  p1 += __shfl_xor(p1, 1, 64);
        p0 += __shfl_xor(p0, 2, 64);  p1 += __shfl_xor(p1, 2, 64);
        p0 += __shfl_xor(p0, 4, 64);  p1 += __shfl_xor(p1, 4, 64);
        p0 += __shfl_xor(p0, 8, 64);  p1 += __shfl_xor(p1, 8, 64);
        if (l15 == 0) {
            lgt[(size_t)e0 * HEADS + q] = p0;
            if (hasB) lgt[(size_t)(e0 + 1) * HEADS + q] = p1;
        }
    }
}

// ====== per-node: softmax + weighted gather-sum + h += elu(.) + LN stats ====
__launch_bounds__(256, 4)
__global__ void agg_kernel(const unsigned short* __restrict__ xl, const float* __restrict__ logits,
                           const int* __restrict__ src, const int* __restrict__ eid,
                           const unsigned* __restrict__ offs, const float* __restrict__ bconv,
                           float* __restrict__ h, float* __restrict__ red) {
    __shared__ float s_sum[4], s_sq[4];
    const int wave = threadIdx.x >> 6, lane = threadIdx.x & 63;
    const int n = blockIdx.x * 4 + wave;
    const unsigned o0 = offs[n], o1 = offs[n + 1];
    const int dg = (int)(o1 - o0);

    const int headA = lane & 3;
    const int slot  = lane >> 2;
    float mx = -1e30f;
    for (int j = slot; j < dg; j += 16) {
        int e = eid[o0 + j];
        mx = fmaxf(mx, logits[(size_t)e * HEADS + headA]);
    }
    mx = fmaxf(mx, __shfl_xor(mx, 4, 64));
    mx = fmaxf(mx, __shfl_xor(mx, 8, 64));
    mx = fmaxf(mx, __shfl_xor(mx, 16, 64));
    mx = fmaxf(mx, __shfl_xor(mx, 32, 64));
    float dn = 0.f;
    for (int j = slot; j < dg; j += 16) {
        int e = eid[o0 + j];
        dn += expf(logits[(size_t)e * HEADS + headA] - mx);
    }
    dn += __shfl_xor(dn, 4, 64);
    dn += __shfl_xor(dn, 8, 64);
    dn += __shfl_xor(dn, 16, 64);
    dn += __shfl_xor(dn, 32, 64);
    const int headC = lane >> 4;
    const float mxC  = __shfl(mx, headC, 64);
    const float idnC = 1.f / (__shfl(dn, headC, 64) + 1e-16f);
    const int c0 = lane * 4;
    float4 acc = make_float4(0.f, 0.f, 0.f, 0.f);

    int j = 0;
    for (; j + 4 <= dg; j += 4) {
        int e0 = eid[o0 + j + 0];
        int e1 = eid[o0 + j + 1];
        int e2 = eid[o0 + j + 2];
        int e3 = eid[o0 + j + 3];
        int s0 = (e0 < N_EDGES) ? src[e0] : n;
        int s1 = (e1 < N_EDGES) ? src[e1] : n;
        int s2 = (e2 < N_EDGES) ? src[e2] : n;
        int s3 = (e3 < N_EDGES) ? src[e3] : n;
        float l0 = logits[(size_t)e0 * HEADS + headC];
        float l1 = logits[(size_t)e1 * HEADS + headC];
        float l2 = logits[(size_t)e2 * HEADS + headC];
        float l3 = logits[(size_t)e3 * HEADS + headC];
        ushort4 x0 = *(const ushort4*)(xl + (size_t)s0 * 256 + c0);
        ushort4 x1 = *(const ushort4*)(xl + (size_t)s1 * 256 + c0);
        ushort4 x2 = *(const ushort4*)(xl + (size_t)s2 * 256 + c0);
        ushort4 x3 = *(const ushort4*)(xl + (size_t)s3 * 256 + c0);
        float a0 = expf(l0 - mxC) * idnC;
        float a1 = expf(l1 - mxC) * idnC;
        float a2 = expf(l2 - mxC) * idnC;
        float a3 = expf(l3 - mxC) * idnC;
        acc.x += a0 * b2f(x0.x) + a1 * b2f(x1.x) + a2 * b2f(x2.x) + a3 * b2f(x3.x);
        acc.y += a0 * b2f(x0.y) + a1 * b2f(x1.y) + a2 * b2f(x2.y) + a3 * b2f(x3.y);
        acc.z += a0 * b2f(x0.z) + a1 * b2f(x1.z) + a2 * b2f(x2.z) + a3 * b2f(x3.z);
        acc.w += a0 * b2f(x0.w) + a1 * b2f(x1.w) + a2 * b2f(x2.w) + a3 * b2f(x3.w);
    }
    for (; j < dg; ++j) {
        int e = eid[o0 + j];
        int s = (e < N_EDGES) ? src[e] : n;
        float alpha = expf(logits[(size_t)e * HEADS + headC] - mxC) * idnC;
        ushort4 xlv = *(const ushort4*)(xl + (size_t)s * 256 + c0);
        acc.x += alpha * b2f(xlv.x); acc.y += alpha * b2f(xlv.y);
        acc.z += alpha * b2f(xlv.z); acc.w += alpha * b2f(xlv.w);
    }

    float* hp = h + (size_t)n * HID + c0;
    float4 hv = *reinterpret_cast<const float4*>(hp);
    const float4 bv = *reinterpret_cast<const float4*>(bconv + c0);
    float v0 = acc.x + bv.x; v0 = v0 > 0.f ? v0 : expm1f(v0);
    float v1 = acc.y + bv.y; v1 = v1 > 0.f ? v1 : expm1f(v1);
    float v2 = acc.z + bv.z; v2 = v2 > 0.f ? v2 : expm1f(v2);
    float v3 = acc.w + bv.w; v3 = v3 > 0.f ? v3 : expm1f(v3);
    float h0 = hv.x + v0, h1 = hv.y + v1, h2 = hv.z + v2, h3 = hv.w + v3;
    *reinterpret_cast<float4*>(hp) = make_float4(h0, h1, h2, h3);
    float sm = h0 + h1 + h2 + h3;
    float sq = h0 * h0 + h1 * h1 + h2 * h2 + h3 * h3;
#pragma unroll
    for (int o = 32; o; o >>= 1) {
        sm += __shfl_down(sm, o, 64);
        sq += __shfl_down(sq, o, 64);
    }
    if (lane == 0) { s_sum[wave] = sm; s_sq[wave] = sq; }
    __syncthreads();
    if (threadIdx.x == 0) {
        atomicAdd(red + 0, s_sum[0] + s_sum[1] + s_sum[2] + s_sum[3]);
        atomicAdd(red + 1, s_sq[0] + s_sq[1] + s_sq[2] + s_sq[3]);
    }
}

// ================= graph layernorm apply (writes f32 + bf16) ================
__global__ void ln_kernel(float* __restrict__ h, unsigned short* __restrict__ hb,
                          const float* __restrict__ red,
                          const float* __restrict__ lnw, const float* __restrict__ lnb) {
    size_t i = (size_t)blockIdx.x * 256 + threadIdx.x;
    int col = (int)(i & 255);
    const float inv_cnt = 1.f / (float)((size_t)N_NODES * HID);
    float mu = red[0] * inv_cnt;
    float ms = red[1] * inv_cnt - mu * mu;
    float stdv = sqrtf(fmaxf(ms, 0.f));
    float sc = 1.f / (stdv + LN_EPS);
    float v = (h[i] - mu) * sc * lnw[col] + lnb[col];
    h[i] = v;
    hb[i] = f2b(v);
}

extern "C" void kernel_launch(void* const* d_in, const int* in_sizes, int n_in,
                              void* d_out, int out_size, void* d_ws, size_t ws_size,
                              hipStream_t stream) {
    (void)in_sizes; (void)n_in; (void)out_size; (void)ws_size;
    const float* x      = (const float*)d_in[0];
    const int*   ei     = (const int*)d_in[1];
    const float* eattr  = (const float*)d_in[2];
    const float* w_in   = (const float*)d_in[3];
    const float* b_in   = (const float*)d_in[4];
    const float* wl     = (const float*)d_in[5];
    const float* wr     = (const float*)d_in[6];
    const float* we     = (const float*)d_in[7];
    const float* att    = (const float*)d_in[8];
    const float* b_conv = (const float*)d_in[9];
    const float* ln_w   = (const float*)d_in[10];
    const float* ln_b   = (const float*)d_in[11];
    const float* w_out  = (const float*)d_in[12];
    const float* b_out  = (const float*)d_in[13];
    const int* srcp = ei;
    const int* dstp = ei + N_EDGES;

    float* ws = (float*)d_ws;
    float*          h    = ws;
    unsigned short* hb   = (unsigned short*)(ws + 12800000);
    unsigned short* xl   = (unsigned short*)(ws + 19200000);
    unsigned short* xr   = (unsigned short*)(ws + 25600000);
    float*          lpea = ws + 32000000;
    float*          lgt  = ws + 33600000;
    unsigned short* wT   = (unsigned short*)(ws + 37000000);
    unsigned*       cnt  = (unsigned*)(ws + 37222000);
    unsigned*       offs = (unsigned*)(ws + 37272000);
    unsigned*       fill = (unsigned*)(ws + 37322002);
    int*            eid  = (int*)(ws + 37372002);
    float*          red  = ws + 38222002;

    unsigned short* w_inT  = wT;            // [256][384]
    unsigned short* wlT0   = wT + 98304;    // [256][256]
    unsigned short* wlT1   = wT + 163840;
    unsigned short* wrT0   = wT + 229376;
    unsigned short* wrT1   = wT + 294912;
    unsigned short* w_outT = wT + 360448;
    unsigned short* weT0   = wT + 425984;   // [256][32]
    unsigned short* weT1   = wT + 434176;

    // ---- CSR build ----
    hipMemsetAsync(cnt, 0, 50000 * sizeof(unsigned), stream);
    hipMemsetAsync(fill, 0, 50000 * sizeof(unsigned), stream);
    csr_count_kernel<<<dim3((N_EDGES + 255) / 256), dim3(256), 0, stream>>>(dstp, cnt);
    csr_scan_kernel<<<dim3(1), dim3(1024), 0, stream>>>(cnt, offs);
    csr_fill_kernel<<<dim3((ETOT + 255) / 256), dim3(256), 0, stream>>>(dstp, offs, fill, eid);
    loopea_csr_kernel<<<dim3(N_NODES / 4), dim3(256), 0, stream>>>(eattr, eid, offs, lpea);

    // ---- weight conversion/transpose ----
    cvt_wT_kernel<<<dim3(384), dim3(256), 0, stream>>>(w_in, w_inT, 98304, 384);
    cvt_wT_kernel<<<dim3(256), dim3(256), 0, stream>>>(wl, wlT0, 65536, 256);
    cvt_wT_kernel<<<dim3(256), dim3(256), 0, stream>>>(wl + 65536, wlT1, 65536, 256);
    cvt_wT_kernel<<<dim3(256), dim3(256), 0, stream>>>(wr, wrT0, 65536, 256);
    cvt_wT_kernel<<<dim3(256), dim3(256), 0, stream>>>(wr + 65536, wrT1, 65536, 256);
    cvt_wT_kernel<<<dim3(256), dim3(256), 0, stream>>>(w_out, w_outT, 65536, 256);
    cvt_wT_kernel<<<dim3(32), dim3(256), 0, stream>>>(we, weT0, 8192, 32);
    cvt_wT_kernel<<<dim3(32), dim3(256), 0, stream>>>(we + 8192, weT1, 8192, 32);

    const int GB = (N_NODES + 63) / 64;   // 782

    mfma_gemm_kernel<true, true, true, true><<<dim3(GB), dim3(256), 0, stream>>>(
        x, w_inT, b_in, h, hb, N_NODES, DIN);

    for (int l = 0; l < 2; ++l) {
        hipMemsetAsync(red, 0, 2 * sizeof(float), stream);
        const unsigned short* wlT = l ? wlT1 : wlT0;
        const unsigned short* wrT = l ? wrT1 : wrT0;
        const unsigned short* weT = l ? weT1 : weT0;
        mfma_gemm_kernel<false, false, false, true><<<dim3(GB), dim3(256), 0, stream>>>(
            hb, wlT, nullptr, nullptr, xl, N_NODES, HID);
        mfma_gemm_kernel<false, false, false, true><<<dim3(GB), dim3(256), 0, stream>>>(
            hb, wrT, nullptr, nullptr, xr, N_NODES, HID);
        edge_mfma_kernel<<<dim3((ETOT + 63) / 64), dim3(256), 0, stream>>>(
            eattr, lpea, xl, xr, srcp, dstp, weT, att + (size_t)l * HID, lgt);
        agg_kernel<<<dim3(N_NODES / 4), dim3(256), 0, stream>>>(
            xl, lgt, srcp, eid, offs, b_conv + (size_t)l * HID, h, red);
        ln_kernel<<<dim3(N_NODES), dim3(256), 0, stream>>>(
            h, hb, red, ln_w + (size_t)l * HID, ln_b + (size_t)l * HID);
    }

    mfma_gemm_kernel<false, false, true, false><<<dim3(GB), dim3(256), 0, stream>>>(
        hb, w_outT, b_out, (float*)d_out, nullptr, N_NODES, HID);
}